// Round 2
// baseline (14437.846 us; speedup 1.0000x reference)
//
#include <hip/hip_runtime.h>
#include <math.h>

#define T_LEN 512
#define BATCH 64
#define HID 128
#define G4 512   // 4*HID

// bf16-packed decoder weight block offsets (elements)
#define OFF_WQ    0          // 128x128
#define OFF_OW    16384      // 128x128
#define OFF_WIH0  32768      // 512x256
#define OFF_WHH0  163840     // 512x128
#define OFF_WIH1  229376     // 512x128
#define OFF_WHH1  294912     // 512x128
#define W_TOTAL   360448

__device__ __forceinline__ float sigf(float x) { return 1.0f / (1.0f + __expf(-x)); }

__device__ __forceinline__ unsigned short f2bf(float x) {
    unsigned u = __float_as_uint(x);
    unsigned r = (u + 0x7fffu + ((u >> 16) & 1u)) >> 16;
    return (unsigned short)r;
}

__device__ __forceinline__ void cvt8(uint4 u, float f[8]) {
    f[0] = __uint_as_float(u.x << 16); f[1] = __uint_as_float(u.x & 0xffff0000u);
    f[2] = __uint_as_float(u.y << 16); f[3] = __uint_as_float(u.y & 0xffff0000u);
    f[4] = __uint_as_float(u.z << 16); f[5] = __uint_as_float(u.z & 0xffff0000u);
    f[6] = __uint_as_float(u.w << 16); f[7] = __uint_as_float(u.w & 0xffff0000u);
}

// ---------------------------------------------------------------------------
// C[M,N] = A[M,K] @ W[N,K]^T + bias[N]   (fp32, 128x128 tile, 8x8 microtile)
// ---------------------------------------------------------------------------
__global__ __launch_bounds__(256) void gemm_bias(
    const float* __restrict__ A, const float* __restrict__ W,
    const float* __restrict__ bias, float* __restrict__ C,
    int M, int N, int K)
{
    __shared__ __align__(16) float As[16][128];
    __shared__ __align__(16) float Ws[16][128];
    const int tid = threadIdx.x;
    const int m0 = blockIdx.y * 128;
    const int n0 = blockIdx.x * 128;
    const int tx = tid & 15, ty = tid >> 4;
    const int lrow = tid >> 1, lk = (tid & 1) * 8;
    float acc[8][8] = {};
    for (int k0 = 0; k0 < K; k0 += 16) {
        const float* Ap = A + (size_t)(m0 + lrow) * K + k0 + lk;
        const float* Wp = W + (size_t)(n0 + lrow) * K + k0 + lk;
        float4 a0 = *(const float4*)Ap;
        float4 a1 = *(const float4*)(Ap + 4);
        float4 w0 = *(const float4*)Wp;
        float4 w1 = *(const float4*)(Wp + 4);
        __syncthreads();
        As[lk+0][lrow]=a0.x; As[lk+1][lrow]=a0.y; As[lk+2][lrow]=a0.z; As[lk+3][lrow]=a0.w;
        As[lk+4][lrow]=a1.x; As[lk+5][lrow]=a1.y; As[lk+6][lrow]=a1.z; As[lk+7][lrow]=a1.w;
        Ws[lk+0][lrow]=w0.x; Ws[lk+1][lrow]=w0.y; Ws[lk+2][lrow]=w0.z; Ws[lk+3][lrow]=w0.w;
        Ws[lk+4][lrow]=w1.x; Ws[lk+5][lrow]=w1.y; Ws[lk+6][lrow]=w1.z; Ws[lk+7][lrow]=w1.w;
        __syncthreads();
        #pragma unroll
        for (int kk = 0; kk < 16; ++kk) {
            float4 av0 = *(const float4*)&As[kk][ty*8];
            float4 av1 = *(const float4*)&As[kk][ty*8+4];
            float4 wv0 = *(const float4*)&Ws[kk][tx*8];
            float4 wv1 = *(const float4*)&Ws[kk][tx*8+4];
            float av[8] = {av0.x,av0.y,av0.z,av0.w,av1.x,av1.y,av1.z,av1.w};
            float wv[8] = {wv0.x,wv0.y,wv0.z,wv0.w,wv1.x,wv1.y,wv1.z,wv1.w};
            #pragma unroll
            for (int i = 0; i < 8; ++i)
                #pragma unroll
                for (int j = 0; j < 8; ++j)
                    acc[i][j] = fmaf(av[i], wv[j], acc[i][j]);
        }
    }
    float bj[8];
    #pragma unroll
    for (int j = 0; j < 8; ++j) bj[j] = bias[n0 + tx*8 + j];
    #pragma unroll
    for (int i = 0; i < 8; ++i) {
        float* cp = C + (size_t)(m0 + ty*8 + i) * N + n0 + tx*8;
        *(float4*)cp     = make_float4(acc[i][0]+bj[0], acc[i][1]+bj[1], acc[i][2]+bj[2], acc[i][3]+bj[3]);
        *(float4*)(cp+4) = make_float4(acc[i][4]+bj[4], acc[i][5]+bj[5], acc[i][6]+bj[6], acc[i][7]+bj[7]);
    }
}

// ---------------------------------------------------------------------------
// LSTM recurrence, one workgroup per batch element, with X prefetch.
// ---------------------------------------------------------------------------
__global__ __launch_bounds__(512) void lstm_rec(
    const float* __restrict__ X,
    const float* __restrict__ Whh,
    float* __restrict__ Hout)
{
    const int b = blockIdx.x;
    const int r = threadIdx.x;
    __shared__ __align__(16) float h_s[HID];
    __shared__ float gate_s[G4];
    float w[HID];
    #pragma unroll
    for (int k = 0; k < HID; k += 4) {
        float4 v = *(const float4*)(Whh + (size_t)r * HID + k);
        w[k] = v.x; w[k+1] = v.y; w[k+2] = v.z; w[k+3] = v.w;
    }
    float c = 0.f;
    if (r < HID) h_s[r] = 0.f;
    __syncthreads();
    float xv = X[(size_t)b * G4 + r];
    for (int t = 0; t < T_LEN; ++t) {
        float xnext = 0.f;
        if (t + 1 < T_LEN) xnext = X[(size_t)((t + 1) * BATCH + b) * G4 + r];
        float a0 = xv, a1 = 0.f, a2 = 0.f, a3 = 0.f;
        const float4* h4 = (const float4*)h_s;
        #pragma unroll
        for (int k = 0; k < HID/4; ++k) {
            float4 hv = h4[k];
            a0 = fmaf(w[4*k+0], hv.x, a0);
            a1 = fmaf(w[4*k+1], hv.y, a1);
            a2 = fmaf(w[4*k+2], hv.z, a2);
            a3 = fmaf(w[4*k+3], hv.w, a3);
        }
        gate_s[r] = (a0 + a1) + (a2 + a3);
        __syncthreads();
        if (r < HID) {
            float gi = gate_s[r], gf = gate_s[HID+r], gg = gate_s[2*HID+r], go = gate_s[3*HID+r];
            c = sigf(gf) * c + sigf(gi) * tanhf(gg);
            float h = sigf(go) * tanhf(c);
            h_s[r] = h;
            Hout[(size_t)(t * BATCH + b) * HID + r] = h;
        }
        __syncthreads();
        xv = xnext;
    }
}

// ---------------------------------------------------------------------------
// KV repack: KVf (t*B+b, 256) fp32 -> Kb[b][t][128] bf16, Vt[b][d][512] bf16
// grid: 64 b * 4 t-chunks, 256 threads
// ---------------------------------------------------------------------------
__global__ __launch_bounds__(256) void kv_pack(
    const float* __restrict__ KVf, unsigned short* __restrict__ Kb,
    unsigned short* __restrict__ Vt)
{
    const int b = blockIdx.x & 63, tc = blockIdx.x >> 6;
    const int t0 = tc * 128;
    __shared__ unsigned short tile[128][130];
    const int half = threadIdx.x >> 7;      // 0/1
    const int d = threadIdx.x & 127;
    for (int tt = 0; tt < 128; tt += 2) {
        int trow = tt + half;
        int t = t0 + trow;
        const float* src = KVf + ((size_t)t * BATCH + b) * 256;
        Kb[((size_t)b * T_LEN + t) * HID + d] = f2bf(src[d]);
        tile[trow][d] = f2bf(src[128 + d]);
    }
    __syncthreads();
    for (int dd = 0; dd < 128; dd += 2) {
        int drow = dd + half;
        int ts = threadIdx.x & 127;
        Vt[((size_t)b * HID + drow) * T_LEN + t0 + ts] = tile[ts][drow];
    }
}

// ---------------------------------------------------------------------------
// Pack decoder weights fp32 -> bf16 block
// ---------------------------------------------------------------------------
__global__ __launch_bounds__(256) void pack_w(
    const float* __restrict__ wq, const float* __restrict__ ow,
    const float* __restrict__ wih0, const float* __restrict__ whh0,
    const float* __restrict__ wih1, const float* __restrict__ whh1,
    unsigned short* __restrict__ Wb)
{
    int i = blockIdx.x * 256 + threadIdx.x;
    if (i >= W_TOTAL) return;
    float v;
    if      (i < OFF_OW)   v = wq[i];
    else if (i < OFF_WIH0) v = ow[i - OFF_OW];
    else if (i < OFF_WHH0) v = wih0[i - OFF_WIH0];
    else if (i < OFF_WIH1) v = whh0[i - OFF_WHH0];
    else if (i < OFF_WHH1) v = wih1[i - OFF_WIH1];
    else                   v = whh1[i - OFF_WHH1];
    Wb[i] = f2bf(v);
}

// ---------------------------------------------------------------------------
// Decoder: one WG per batch, 64 steps. KV + weights bf16, L2-resident.
// ---------------------------------------------------------------------------
__global__ __launch_bounds__(512) void decoder2(
    const unsigned short* __restrict__ Kb, const unsigned short* __restrict__ Vt,
    const unsigned short* __restrict__ Wb,
    const float* __restrict__ attn_b, const float* __restrict__ ob,
    const float* __restrict__ b0, const float* __restrict__ b1,
    const float* __restrict__ lw, const float* __restrict__ lb,
    float* __restrict__ Y)
{
    const int b = blockIdx.x;
    const int tid = threadIdx.x;
    __shared__ __align__(16) float out_s[HID];
    __shared__ __align__(16) float q_s[HID];
    __shared__ __align__(16) float sc[4 * T_LEN];
    __shared__ float red[512];
    __shared__ __align__(16) float ctxp[4][HID];
    __shared__ __align__(16) float ctx_s[HID];
    __shared__ __align__(16) float x_s[2 * HID];
    __shared__ __align__(16) float h0_s[HID];
    __shared__ __align__(16) float h1_s[HID];
    __shared__ float gate_s[G4];
    __shared__ float hmax[4], hden[4];
    float c0 = 0.f, c1 = 0.f;
    if (tid < HID) { out_s[tid] = 0.f; h0_s[tid] = 0.f; h1_s[tid] = 0.f; }
    __syncthreads();
    const float scale = 0.17677669529663687f;   // 1/sqrt(32)
    const int g = tid >> 7, l = tid & 127;

    for (int step = 0; step < 64; ++step) {
        // ---- q = (out @ Wq.T + bq) * scale ----
        if (tid < HID) {
            const unsigned short* wr = Wb + OFF_WQ + (size_t)tid * HID;
            float acc = attn_b[tid];
            #pragma unroll
            for (int k = 0; k < HID; k += 8) {
                float f[8]; cvt8(*(const uint4*)(wr + k), f);
                float4 o0 = *(const float4*)(out_s + k);
                float4 o1 = *(const float4*)(out_s + k + 4);
                acc += f[0]*o0.x + f[1]*o0.y + f[2]*o0.z + f[3]*o0.w
                     + f[4]*o1.x + f[5]*o1.y + f[6]*o1.z + f[7]*o1.w;
            }
            q_s[tid] = acc * scale;
        }
        __syncthreads();
        // ---- scores: thread t = tid, all 4 heads (K row bf16, contiguous) ----
        {
            const unsigned short* kr = Kb + ((size_t)b * T_LEN + tid) * HID;
            float acc[4] = {0.f, 0.f, 0.f, 0.f};
            #pragma unroll
            for (int k = 0; k < HID; k += 8) {
                float f[8]; cvt8(*(const uint4*)(kr + k), f);
                float4 q0 = *(const float4*)(q_s + k);
                float4 q1 = *(const float4*)(q_s + k + 4);
                acc[k >> 5] += f[0]*q0.x + f[1]*q0.y + f[2]*q0.z + f[3]*q0.w
                             + f[4]*q1.x + f[5]*q1.y + f[6]*q1.z + f[7]*q1.w;
            }
            #pragma unroll
            for (int h = 0; h < 4; ++h) sc[h * T_LEN + tid] = acc[h];
        }
        __syncthreads();
        // ---- softmax per head (head g owned by 128-thread group g) ----
        float v[4];
        float mx = -3.4e38f;
        #pragma unroll
        for (int i = 0; i < 4; ++i) { v[i] = sc[g*T_LEN + l + 128*i]; mx = fmaxf(mx, v[i]); }
        red[tid] = mx;
        __syncthreads();
        if (l < 64) {
            float m2 = fmaxf(red[g*128 + l], red[g*128 + l + 64]);
            #pragma unroll
            for (int s = 32; s > 0; s >>= 1) m2 = fmaxf(m2, __shfl_xor(m2, s, 64));
            if (l == 0) hmax[g] = m2;
        }
        __syncthreads();
        float hm = hmax[g];
        float s4 = 0.f;
        #pragma unroll
        for (int i = 0; i < 4; ++i) {
            float e = __expf(v[i] - hm);
            sc[g*T_LEN + l + 128*i] = e;
            s4 += e;
        }
        red[tid] = s4;
        __syncthreads();
        if (l < 64) {
            float s2 = red[g*128 + l] + red[g*128 + l + 64];
            #pragma unroll
            for (int s = 32; s > 0; s >>= 1) s2 += __shfl_xor(s2, s, 64);
            if (l == 0) hden[g] = s2;
        }
        __syncthreads();
        // ---- ctx: thread (d = tid&127, chunk = tid>>7); V d-major bf16 ----
        {
            const int d = tid & 127, ch = tid >> 7;
            const unsigned short* vr = Vt + ((size_t)b * HID + d) * T_LEN + ch * 128;
            const float* scr = sc + (d >> 5) * T_LEN + ch * 128;
            float acc = 0.f;
            #pragma unroll
            for (int k = 0; k < 128; k += 8) {
                float f[8]; cvt8(*(const uint4*)(vr + k), f);
                #pragma unroll
                for (int j = 0; j < 8; ++j) acc = fmaf(f[j], scr[k + j], acc);
            }
            ctxp[ch][d] = acc;
        }
        __syncthreads();
        if (tid < HID)
            ctx_s[tid] = (ctxp[0][tid] + ctxp[1][tid] + ctxp[2][tid] + ctxp[3][tid]) / hden[tid >> 5];
        __syncthreads();
        // ---- out-projection, x = [out, ctx_proj] ----
        if (tid < HID) {
            const unsigned short* wr = Wb + OFF_OW + (size_t)tid * HID;
            float acc = ob[tid];
            #pragma unroll
            for (int k = 0; k < HID; k += 8) {
                float f[8]; cvt8(*(const uint4*)(wr + k), f);
                float4 c0v = *(const float4*)(ctx_s + k);
                float4 c1v = *(const float4*)(ctx_s + k + 4);
                acc += f[0]*c0v.x + f[1]*c0v.y + f[2]*c0v.z + f[3]*c0v.w
                     + f[4]*c1v.x + f[5]*c1v.y + f[6]*c1v.z + f[7]*c1v.w;
            }
            x_s[HID + tid] = acc;
            x_s[tid] = out_s[tid];
        }
        __syncthreads();
        // ---- decoder LSTM layer 0 gates ----
        {
            const unsigned short* wi = Wb + OFF_WIH0 + (size_t)tid * 256;
            const unsigned short* wh = Wb + OFF_WHH0 + (size_t)tid * HID;
            float acc = b0[tid];
            #pragma unroll
            for (int k = 0; k < 256; k += 8) {
                float f[8]; cvt8(*(const uint4*)(wi + k), f);
                float4 x0 = *(const float4*)(x_s + k);
                float4 x1 = *(const float4*)(x_s + k + 4);
                acc += f[0]*x0.x + f[1]*x0.y + f[2]*x0.z + f[3]*x0.w
                     + f[4]*x1.x + f[5]*x1.y + f[6]*x1.z + f[7]*x1.w;
            }
            #pragma unroll
            for (int k = 0; k < HID; k += 8) {
                float f[8]; cvt8(*(const uint4*)(wh + k), f);
                float4 h0 = *(const float4*)(h0_s + k);
                float4 h1 = *(const float4*)(h0_s + k + 4);
                acc += f[0]*h0.x + f[1]*h0.y + f[2]*h0.z + f[3]*h0.w
                     + f[4]*h1.x + f[5]*h1.y + f[6]*h1.z + f[7]*h1.w;
            }
            gate_s[tid] = acc;
        }
        __syncthreads();
        if (tid < HID) {
            float gi = gate_s[tid], gf = gate_s[HID+tid], gg = gate_s[2*HID+tid], go = gate_s[3*HID+tid];
            c0 = sigf(gf) * c0 + sigf(gi) * tanhf(gg);
            h0_s[tid] = sigf(go) * tanhf(c0);
        }
        __syncthreads();
        // ---- decoder LSTM layer 1 gates ----
        {
            const unsigned short* wi = Wb + OFF_WIH1 + (size_t)tid * HID;
            const unsigned short* wh = Wb + OFF_WHH1 + (size_t)tid * HID;
            float acc = b1[tid];
            #pragma unroll
            for (int k = 0; k < HID; k += 8) {
                float f[8]; cvt8(*(const uint4*)(wi + k), f);
                float4 h0 = *(const float4*)(h0_s + k);
                float4 h1 = *(const float4*)(h0_s + k + 4);
                acc += f[0]*h0.x + f[1]*h0.y + f[2]*h0.z + f[3]*h0.w
                     + f[4]*h1.x + f[5]*h1.y + f[6]*h1.z + f[7]*h1.w;
            }
            #pragma unroll
            for (int k = 0; k < HID; k += 8) {
                float f[8]; cvt8(*(const uint4*)(wh + k), f);
                float4 h0 = *(const float4*)(h1_s + k);
                float4 h1 = *(const float4*)(h1_s + k + 4);
                acc += f[0]*h0.x + f[1]*h0.y + f[2]*h0.z + f[3]*h0.w
                     + f[4]*h1.x + f[5]*h1.y + f[6]*h1.z + f[7]*h1.w;
            }
            gate_s[tid] = acc;
        }
        __syncthreads();
        if (tid < HID) {
            float gi = gate_s[tid], gf = gate_s[HID+tid], gg = gate_s[2*HID+tid], go = gate_s[3*HID+tid];
            c1 = sigf(gf) * c1 + sigf(gi) * tanhf(gg);
            float h = sigf(go) * tanhf(c1);
            h1_s[tid] = h;
            out_s[tid] = fmaxf(h, 0.f);
        }
        __syncthreads();
        // ---- y = relu(h1) @ lin_w.T + lin_b   (fp32 weights, tiny) ----
        if (tid < 3) {
            const float* wr = lw + (size_t)tid * HID;
            float acc = lb[tid];
            #pragma unroll
            for (int k = 0; k < HID; k += 4) {
                float4 wv = *(const float4*)(wr + k);
                float4 ov = *(const float4*)(out_s + k);
                acc += wv.x*ov.x + wv.y*ov.y + wv.z*ov.z + wv.w*ov.w;
            }
            Y[((size_t)step * BATCH + b) * 3 + tid] = acc;
        }
        __syncthreads();
    }
}

// ---------------------------------------------------------------------------
extern "C" void kernel_launch(void* const* d_in, const int* in_sizes, int n_in,
                              void* d_out, int out_size, void* d_ws, size_t ws_size,
                              hipStream_t stream) {
    const float* cnn        = (const float*)d_in[0];
    const float* eWih0      = (const float*)d_in[1];
    const float* eWhh0      = (const float*)d_in[2];
    const float* eb0        = (const float*)d_in[3];
    const float* eWih1      = (const float*)d_in[4];
    const float* eWhh1      = (const float*)d_in[5];
    const float* eb1        = (const float*)d_in[6];
    const float* attn_in_w  = (const float*)d_in[7];
    const float* attn_in_b  = (const float*)d_in[8];
    const float* attn_out_w = (const float*)d_in[9];
    const float* attn_out_b = (const float*)d_in[10];
    const float* dWih0      = (const float*)d_in[11];
    const float* dWhh0      = (const float*)d_in[12];
    const float* db0        = (const float*)d_in[13];
    const float* dWih1      = (const float*)d_in[14];
    const float* dWhh1      = (const float*)d_in[15];
    const float* db1        = (const float*)d_in[16];
    const float* lin_w      = (const float*)d_in[17];
    const float* lin_b      = (const float*)d_in[18];
    float* Y  = (float*)d_out;

    // ws layout: X (32768*512 f32) | Hb (32768*128 f32) | Kb,Vt,Wb (bf16)
    float* ws = (float*)d_ws;
    float* X  = ws;                                  // 64 MiB (also KVf scratch)
    float* Hb = X + (size_t)32768 * 512;             // 16 MiB
    unsigned short* Kb = (unsigned short*)(Hb + (size_t)32768 * 128);   // 8 MiB
    unsigned short* Vt = Kb + (size_t)BATCH * T_LEN * HID;              // 8 MiB
    unsigned short* Wb = Vt + (size_t)BATCH * HID * T_LEN;              // ~0.7 MiB

    const int M = T_LEN * BATCH;  // 32768

    pack_w<<<(W_TOTAL + 255) / 256, 256, 0, stream>>>(
        attn_in_w, attn_out_w, dWih0, dWhh0, dWih1, dWhh1, Wb);

    // encoder layer 0
    gemm_bias<<<dim3(4, M/128), 256, 0, stream>>>(cnn, eWih0, eb0, X, M, 512, 1024);
    lstm_rec<<<BATCH, 512, 0, stream>>>(X, eWhh0, Hb);
    // encoder layer 1
    gemm_bias<<<dim3(4, M/128), 256, 0, stream>>>(Hb, eWih1, eb1, X, M, 512, 128);
    lstm_rec<<<BATCH, 512, 0, stream>>>(X, eWhh1, Hb);   // Hb = enc
    // KV = enc @ [Wk;Wv]^T + [bk;bv]  -> fp32 scratch in X
    gemm_bias<<<dim3(2, M/128), 256, 0, stream>>>(Hb, attn_in_w + 128*128, attn_in_b + 128,
                                                  X, M, 256, 128);
    kv_pack<<<256, 256, 0, stream>>>(X, Kb, Vt);
    // decoder
    decoder2<<<BATCH, 512, 0, stream>>>(Kb, Vt, Wb,
                                        attn_in_b, attn_out_b, db0, db1, lin_w, lin_b, Y);
}

// Round 3
// 12353.498 us; speedup vs baseline: 1.1687x; 1.1687x over previous
//
#include <hip/hip_runtime.h>
#include <math.h>

#define T_LEN 512
#define BATCH 64
#define HID 128
#define G4 512   // 4*HID

// bf16-packed decoder weight block (elements)
#define OFF_WQ2   0        // Wq            128x128
#define OFF_WXO   16384    // Wih0[:,0:128] 512x128
#define OFF_WXC   81920    // Wih0[:,128:]@Ow fused  512x128
#define OFF_WHH0b 147456   // Whh0          512x128
#define OFF_WIH1b 212992   // Wih1          512x128
#define OFF_WHH1b 278528   // Whh1          512x128
#define W2_TOTAL  344064

__device__ __forceinline__ float sigf(float x) { return 1.0f / (1.0f + __expf(-x)); }

__device__ __forceinline__ unsigned short f2bf(float x) {
    unsigned u = __float_as_uint(x);
    unsigned r = (u + 0x7fffu + ((u >> 16) & 1u)) >> 16;
    return (unsigned short)r;
}

__device__ __forceinline__ void cvt8(uint4 u, float f[8]) {
    f[0] = __uint_as_float(u.x << 16); f[1] = __uint_as_float(u.x & 0xffff0000u);
    f[2] = __uint_as_float(u.y << 16); f[3] = __uint_as_float(u.y & 0xffff0000u);
    f[4] = __uint_as_float(u.z << 16); f[5] = __uint_as_float(u.z & 0xffff0000u);
    f[6] = __uint_as_float(u.w << 16); f[7] = __uint_as_float(u.w & 0xffff0000u);
}

// ---------------------------------------------------------------------------
// C[M,N] = A[M,K] @ W[N,K]^T + bias[N]   (fp32, 128x128 tile, 8x8 microtile)
// ---------------------------------------------------------------------------
__global__ __launch_bounds__(256) void gemm_bias(
    const float* __restrict__ A, const float* __restrict__ W,
    const float* __restrict__ bias, float* __restrict__ C,
    int M, int N, int K)
{
    __shared__ __align__(16) float As[16][128];
    __shared__ __align__(16) float Ws[16][128];
    const int tid = threadIdx.x;
    const int m0 = blockIdx.y * 128;
    const int n0 = blockIdx.x * 128;
    const int tx = tid & 15, ty = tid >> 4;
    const int lrow = tid >> 1, lk = (tid & 1) * 8;
    float acc[8][8] = {};
    for (int k0 = 0; k0 < K; k0 += 16) {
        const float* Ap = A + (size_t)(m0 + lrow) * K + k0 + lk;
        const float* Wp = W + (size_t)(n0 + lrow) * K + k0 + lk;
        float4 a0 = *(const float4*)Ap;
        float4 a1 = *(const float4*)(Ap + 4);
        float4 w0 = *(const float4*)Wp;
        float4 w1 = *(const float4*)(Wp + 4);
        __syncthreads();
        As[lk+0][lrow]=a0.x; As[lk+1][lrow]=a0.y; As[lk+2][lrow]=a0.z; As[lk+3][lrow]=a0.w;
        As[lk+4][lrow]=a1.x; As[lk+5][lrow]=a1.y; As[lk+6][lrow]=a1.z; As[lk+7][lrow]=a1.w;
        Ws[lk+0][lrow]=w0.x; Ws[lk+1][lrow]=w0.y; Ws[lk+2][lrow]=w0.z; Ws[lk+3][lrow]=w0.w;
        Ws[lk+4][lrow]=w1.x; Ws[lk+5][lrow]=w1.y; Ws[lk+6][lrow]=w1.z; Ws[lk+7][lrow]=w1.w;
        __syncthreads();
        #pragma unroll
        for (int kk = 0; kk < 16; ++kk) {
            float4 av0 = *(const float4*)&As[kk][ty*8];
            float4 av1 = *(const float4*)&As[kk][ty*8+4];
            float4 wv0 = *(const float4*)&Ws[kk][tx*8];
            float4 wv1 = *(const float4*)&Ws[kk][tx*8+4];
            float av[8] = {av0.x,av0.y,av0.z,av0.w,av1.x,av1.y,av1.z,av1.w};
            float wv[8] = {wv0.x,wv0.y,wv0.z,wv0.w,wv1.x,wv1.y,wv1.z,wv1.w};
            #pragma unroll
            for (int i = 0; i < 8; ++i)
                #pragma unroll
                for (int j = 0; j < 8; ++j)
                    acc[i][j] = fmaf(av[i], wv[j], acc[i][j]);
        }
    }
    float bj[8];
    #pragma unroll
    for (int j = 0; j < 8; ++j) bj[j] = bias[n0 + tx*8 + j];
    #pragma unroll
    for (int i = 0; i < 8; ++i) {
        float* cp = C + (size_t)(m0 + ty*8 + i) * N + n0 + tx*8;
        *(float4*)cp     = make_float4(acc[i][0]+bj[0], acc[i][1]+bj[1], acc[i][2]+bj[2], acc[i][3]+bj[3]);
        *(float4*)(cp+4) = make_float4(acc[i][4]+bj[4], acc[i][5]+bj[5], acc[i][6]+bj[6], acc[i][7]+bj[7]);
    }
}

// ---------------------------------------------------------------------------
// LSTM recurrence, one workgroup per batch element, with X prefetch.
// ---------------------------------------------------------------------------
__global__ __launch_bounds__(512) void lstm_rec(
    const float* __restrict__ X,
    const float* __restrict__ Whh,
    float* __restrict__ Hout)
{
    const int b = blockIdx.x;
    const int r = threadIdx.x;
    __shared__ __align__(16) float h_s[HID];
    __shared__ float gate_s[G4];
    float w[HID];
    #pragma unroll
    for (int k = 0; k < HID; k += 4) {
        float4 v = *(const float4*)(Whh + (size_t)r * HID + k);
        w[k] = v.x; w[k+1] = v.y; w[k+2] = v.z; w[k+3] = v.w;
    }
    float c = 0.f;
    if (r < HID) h_s[r] = 0.f;
    __syncthreads();
    float xv = X[(size_t)b * G4 + r];
    for (int t = 0; t < T_LEN; ++t) {
        float xnext = 0.f;
        if (t + 1 < T_LEN) xnext = X[(size_t)((t + 1) * BATCH + b) * G4 + r];
        float a0 = xv, a1 = 0.f, a2 = 0.f, a3 = 0.f;
        const float4* h4 = (const float4*)h_s;
        #pragma unroll
        for (int k = 0; k < HID/4; ++k) {
            float4 hv = h4[k];
            a0 = fmaf(w[4*k+0], hv.x, a0);
            a1 = fmaf(w[4*k+1], hv.y, a1);
            a2 = fmaf(w[4*k+2], hv.z, a2);
            a3 = fmaf(w[4*k+3], hv.w, a3);
        }
        gate_s[r] = (a0 + a1) + (a2 + a3);
        __syncthreads();
        if (r < HID) {
            float gi = gate_s[r], gf = gate_s[HID+r], gg = gate_s[2*HID+r], go = gate_s[3*HID+r];
            c = sigf(gf) * c + sigf(gi) * tanhf(gg);
            float h = sigf(go) * tanhf(c);
            h_s[r] = h;
            Hout[(size_t)(t * BATCH + b) * HID + r] = h;
        }
        __syncthreads();
        xv = xnext;
    }
}

// ---------------------------------------------------------------------------
// KV repack: KVf (t*B+b, 256) fp32 -> Kb[b][t][128] bf16, Vt[b][d][512] bf16
// ---------------------------------------------------------------------------
__global__ __launch_bounds__(256) void kv_pack(
    const float* __restrict__ KVf, unsigned short* __restrict__ Kb,
    unsigned short* __restrict__ Vt)
{
    const int b = blockIdx.x & 63, tc = blockIdx.x >> 6;
    const int t0 = tc * 128;
    __shared__ unsigned short tile[128][130];
    const int half = threadIdx.x >> 7;      // 0/1
    const int d = threadIdx.x & 127;
    for (int tt = 0; tt < 128; tt += 2) {
        int trow = tt + half;
        int t = t0 + trow;
        const float* src = KVf + ((size_t)t * BATCH + b) * 256;
        Kb[((size_t)b * T_LEN + t) * HID + d] = f2bf(src[d]);
        tile[trow][d] = f2bf(src[128 + d]);
    }
    __syncthreads();
    for (int dd = 0; dd < 128; dd += 2) {
        int drow = dd + half;
        int ts = threadIdx.x & 127;
        Vt[((size_t)b * HID + drow) * T_LEN + t0 + ts] = tile[ts][drow];
    }
}

// ---------------------------------------------------------------------------
// pack2: fp32 -> bf16 for all decoder weights except the fused W_xc block
// ---------------------------------------------------------------------------
__global__ __launch_bounds__(256) void pack2(
    const float* __restrict__ attn_in_w,
    const float* __restrict__ dWih0, const float* __restrict__ dWhh0,
    const float* __restrict__ dWih1, const float* __restrict__ dWhh1,
    unsigned short* __restrict__ Wb2)
{
    int i = blockIdx.x * 256 + threadIdx.x;
    if (i >= W2_TOTAL) return;
    if (i >= OFF_WXC && i < OFF_WHH0b) return;   // filled by fuse_wxc
    float v;
    if (i < OFF_WXO) v = attn_in_w[i];                       // Wq rows 0..127
    else if (i < OFF_WXC) {
        int j = i - OFF_WXO; v = dWih0[(size_t)(j >> 7) * 256 + (j & 127)];
    }
    else if (i < OFF_WIH1b) v = dWhh0[i - OFF_WHH0b];
    else if (i < OFF_WHH1b) v = dWih1[i - OFF_WIH1b];
    else                    v = dWhh1[i - OFF_WHH1b];
    Wb2[i] = f2bf(v);
}

// ---------------------------------------------------------------------------
// W_xc[r][c] = sum_j Wih0[r][128+j] * Ow[j][c]   (bf16 out)
// grid 256 WGs x 256 thr; WG handles 2 rows
// ---------------------------------------------------------------------------
__global__ __launch_bounds__(256) void fuse_wxc(
    const float* __restrict__ dWih0, const float* __restrict__ ow,
    unsigned short* __restrict__ Wb2)
{
    __shared__ float ow_s[128 * 128];
    for (int i = threadIdx.x; i < 16384; i += 256) ow_s[i] = ow[i];
    __syncthreads();
    const int r = blockIdx.x * 2 + (threadIdx.x >> 7);
    const int c = threadIdx.x & 127;
    const float* wr = dWih0 + (size_t)r * 256 + 128;
    float acc = 0.f;
    #pragma unroll 8
    for (int j = 0; j < 128; ++j) acc = fmaf(wr[j], ow_s[j * 128 + c], acc);
    Wb2[OFF_WXC + r * 128 + c] = f2bf(acc);
}

// b0'[r] = b0[r] + sum_j Wih0[r][128+j] * ob[j]
__global__ __launch_bounds__(128) void fuse_b0(
    const float* __restrict__ dWih0, const float* __restrict__ ob,
    const float* __restrict__ db0, float* __restrict__ b0p)
{
    int r = blockIdx.x * 128 + threadIdx.x;
    const float* wr = dWih0 + (size_t)r * 256 + 128;
    float acc = db0[r];
    #pragma unroll 8
    for (int j = 0; j < 128; ++j) acc = fmaf(wr[j], ob[j], acc);
    b0p[r] = acc;
}

// ---------------------------------------------------------------------------
// Decoder v3: one WG per batch. K in LDS (XOR-swizzled); V + weights from L2.
// ---------------------------------------------------------------------------
__global__ __launch_bounds__(512) void decoder3(
    const unsigned short* __restrict__ Kb, const unsigned short* __restrict__ Vt,
    const unsigned short* __restrict__ Wb2, const float* __restrict__ b0p,
    const float* __restrict__ attn_b, const float* __restrict__ b1,
    const float* __restrict__ lw, const float* __restrict__ lb,
    float* __restrict__ Y)
{
    extern __shared__ __align__(16) char dyn[];
    char* Kl = dyn;                               // 512*128 bf16 swizzled = 128 KiB
    const int b = blockIdx.x;
    const int tid = threadIdx.x;
    __shared__ __align__(16) float out_s[HID];
    __shared__ __align__(16) float q_s[HID];
    __shared__ __align__(16) float sc[4 * T_LEN];
    __shared__ float red[512];
    __shared__ __align__(16) float ctxp[4][HID];
    __shared__ __align__(16) float ctx_s[HID];
    __shared__ __align__(16) float h0_s[HID];
    __shared__ __align__(16) float h1_s[HID];
    __shared__ float gate_s[G4];
    __shared__ float hmax[4], hden[4];

    // ---- stage K into LDS, swizzle: byte k16*16 ^ ((t&7)<<4) within row ----
    {
        const unsigned short* Ksrc = Kb + (size_t)b * T_LEN * HID;
        for (int c = tid; c < T_LEN * HID / 8; c += 512) {
            int t = c >> 4, k16 = c & 15;
            uint4 v = *(const uint4*)(Ksrc + c * 8);
            *(uint4*)(Kl + t * 256 + ((k16 * 16) ^ ((t & 7) << 4))) = v;
        }
    }
    float c0 = 0.f, c1 = 0.f;
    if (tid < HID) { out_s[tid] = 0.f; h0_s[tid] = 0.f; h1_s[tid] = 0.f; }
    __syncthreads();
    const float scale = 0.17677669529663687f;   // 1/sqrt(32)
    const int g = tid >> 7, l = tid & 127;

    for (int step = 0; step < 64; ++step) {
        // ---- q = (Wq @ out + bq) * scale ----
        if (tid < HID) {
            const unsigned short* wr = Wb2 + OFF_WQ2 + (size_t)tid * HID;
            float acc = attn_b[tid];
            #pragma unroll
            for (int k = 0; k < HID; k += 8) {
                float f[8]; cvt8(*(const uint4*)(wr + k), f);
                float4 o0 = *(const float4*)(out_s + k);
                float4 o1 = *(const float4*)(out_s + k + 4);
                acc += f[0]*o0.x + f[1]*o0.y + f[2]*o0.z + f[3]*o0.w
                     + f[4]*o1.x + f[5]*o1.y + f[6]*o1.z + f[7]*o1.w;
            }
            q_s[tid] = acc * scale;
        }
        __syncthreads();
        // ---- scores from LDS K (swizzled), thread t = tid, 4 heads ----
        {
            const int t = tid;
            float acc[4] = {0.f, 0.f, 0.f, 0.f};
            #pragma unroll
            for (int k16 = 0; k16 < 16; ++k16) {
                uint4 u = *(const uint4*)(Kl + t * 256 + ((k16 * 16) ^ ((t & 7) << 4)));
                float f[8]; cvt8(u, f);
                float4 q0 = *(const float4*)(q_s + k16 * 8);
                float4 q1 = *(const float4*)(q_s + k16 * 8 + 4);
                acc[k16 >> 2] += f[0]*q0.x + f[1]*q0.y + f[2]*q0.z + f[3]*q0.w
                               + f[4]*q1.x + f[5]*q1.y + f[6]*q1.z + f[7]*q1.w;
            }
            #pragma unroll
            for (int h = 0; h < 4; ++h) sc[h * T_LEN + t] = acc[h];
        }
        __syncthreads();
        // ---- softmax per head (head g owned by 128-thread group g) ----
        float v[4];
        float mx = -3.4e38f;
        #pragma unroll
        for (int i = 0; i < 4; ++i) { v[i] = sc[g*T_LEN + l + 128*i]; mx = fmaxf(mx, v[i]); }
        red[tid] = mx;
        __syncthreads();
        if (l < 64) {
            float m2 = fmaxf(red[g*128 + l], red[g*128 + l + 64]);
            #pragma unroll
            for (int s = 32; s > 0; s >>= 1) m2 = fmaxf(m2, __shfl_xor(m2, s, 64));
            if (l == 0) hmax[g] = m2;
        }
        __syncthreads();
        float hm = hmax[g];
        float s4 = 0.f;
        #pragma unroll
        for (int i = 0; i < 4; ++i) {
            float e = __expf(v[i] - hm);
            sc[g*T_LEN + l + 128*i] = e;
            s4 += e;
        }
        red[tid] = s4;
        __syncthreads();
        if (l < 64) {
            float s2 = red[g*128 + l] + red[g*128 + l + 64];
            #pragma unroll
            for (int s = 32; s > 0; s >>= 1) s2 += __shfl_xor(s2, s, 64);
            if (l == 0) hden[g] = s2;
        }
        __syncthreads();
        // ---- ctx: thread (d = tid&127, chunk = tid>>7); V d-major from L2 ----
        {
            const int d = tid & 127, ch = tid >> 7;
            const unsigned short* vr = Vt + ((size_t)b * HID + d) * T_LEN + ch * 128;
            const float* scr = sc + (d >> 5) * T_LEN + ch * 128;
            float acc = 0.f;
            #pragma unroll
            for (int k = 0; k < 128; k += 8) {
                float f[8]; cvt8(*(const uint4*)(vr + k), f);
                #pragma unroll
                for (int j = 0; j < 8; ++j) acc = fmaf(f[j], scr[k + j], acc);
            }
            ctxp[ch][d] = acc;
        }
        __syncthreads();
        if (tid < HID)
            ctx_s[tid] = (ctxp[0][tid] + ctxp[1][tid] + ctxp[2][tid] + ctxp[3][tid]) / hden[tid >> 5];
        __syncthreads();
        // ---- layer-0 gates: W_xo@out + W_xc@ctx + Whh0@h0 + b0' ----
        {
            const unsigned short* wxo = Wb2 + OFF_WXO   + (size_t)tid * HID;
            const unsigned short* wxc = Wb2 + OFF_WXC   + (size_t)tid * HID;
            const unsigned short* whh = Wb2 + OFF_WHH0b + (size_t)tid * HID;
            float acc = b0p[tid];
            #pragma unroll
            for (int k = 0; k < HID; k += 8) {
                float f[8]; cvt8(*(const uint4*)(wxo + k), f);
                float4 a0 = *(const float4*)(out_s + k);
                float4 a1 = *(const float4*)(out_s + k + 4);
                acc += f[0]*a0.x + f[1]*a0.y + f[2]*a0.z + f[3]*a0.w
                     + f[4]*a1.x + f[5]*a1.y + f[6]*a1.z + f[7]*a1.w;
            }
            #pragma unroll
            for (int k = 0; k < HID; k += 8) {
                float f[8]; cvt8(*(const uint4*)(wxc + k), f);
                float4 a0 = *(const float4*)(ctx_s + k);
                float4 a1 = *(const float4*)(ctx_s + k + 4);
                acc += f[0]*a0.x + f[1]*a0.y + f[2]*a0.z + f[3]*a0.w
                     + f[4]*a1.x + f[5]*a1.y + f[6]*a1.z + f[7]*a1.w;
            }
            #pragma unroll
            for (int k = 0; k < HID; k += 8) {
                float f[8]; cvt8(*(const uint4*)(whh + k), f);
                float4 a0 = *(const float4*)(h0_s + k);
                float4 a1 = *(const float4*)(h0_s + k + 4);
                acc += f[0]*a0.x + f[1]*a0.y + f[2]*a0.z + f[3]*a0.w
                     + f[4]*a1.x + f[5]*a1.y + f[6]*a1.z + f[7]*a1.w;
            }
            gate_s[tid] = acc;
        }
        __syncthreads();
        if (tid < HID) {
            float gi = gate_s[tid], gf = gate_s[HID+tid], gg = gate_s[2*HID+tid], go = gate_s[3*HID+tid];
            c0 = sigf(gf) * c0 + sigf(gi) * tanhf(gg);
            h0_s[tid] = sigf(go) * tanhf(c0);
        }
        __syncthreads();
        // ---- layer-1 gates ----
        {
            const unsigned short* wi = Wb2 + OFF_WIH1b + (size_t)tid * HID;
            const unsigned short* wh = Wb2 + OFF_WHH1b + (size_t)tid * HID;
            float acc = b1[tid];
            #pragma unroll
            for (int k = 0; k < HID; k += 8) {
                float f[8]; cvt8(*(const uint4*)(wi + k), f);
                float4 a0 = *(const float4*)(h0_s + k);
                float4 a1 = *(const float4*)(h0_s + k + 4);
                acc += f[0]*a0.x + f[1]*a0.y + f[2]*a0.z + f[3]*a0.w
                     + f[4]*a1.x + f[5]*a1.y + f[6]*a1.z + f[7]*a1.w;
            }
            #pragma unroll
            for (int k = 0; k < HID; k += 8) {
                float f[8]; cvt8(*(const uint4*)(wh + k), f);
                float4 a0 = *(const float4*)(h1_s + k);
                float4 a1 = *(const float4*)(h1_s + k + 4);
                acc += f[0]*a0.x + f[1]*a0.y + f[2]*a0.z + f[3]*a0.w
                     + f[4]*a1.x + f[5]*a1.y + f[6]*a1.z + f[7]*a1.w;
            }
            gate_s[tid] = acc;
        }
        __syncthreads();
        if (tid < HID) {
            float gi = gate_s[tid], gf = gate_s[HID+tid], gg = gate_s[2*HID+tid], go = gate_s[3*HID+tid];
            c1 = sigf(gf) * c1 + sigf(gi) * tanhf(gg);
            float h = sigf(go) * tanhf(c1);
            h1_s[tid] = h;
            out_s[tid] = fmaxf(h, 0.f);
        }
        __syncthreads();
        // ---- y = relu(h1) @ lin_w.T + lin_b ----
        if (tid < 3) {
            const float* wr = lw + (size_t)tid * HID;
            float acc = lb[tid];
            #pragma unroll
            for (int k = 0; k < HID; k += 4) {
                float4 wv = *(const float4*)(wr + k);
                float4 ov = *(const float4*)(out_s + k);
                acc += wv.x*ov.x + wv.y*ov.y + wv.z*ov.z + wv.w*ov.w;
            }
            Y[((size_t)step * BATCH + b) * 3 + tid] = acc;
        }
        __syncthreads();
    }
}

// ---------------------------------------------------------------------------
extern "C" void kernel_launch(void* const* d_in, const int* in_sizes, int n_in,
                              void* d_out, int out_size, void* d_ws, size_t ws_size,
                              hipStream_t stream) {
    const float* cnn        = (const float*)d_in[0];
    const float* eWih0      = (const float*)d_in[1];
    const float* eWhh0      = (const float*)d_in[2];
    const float* eb0        = (const float*)d_in[3];
    const float* eWih1      = (const float*)d_in[4];
    const float* eWhh1      = (const float*)d_in[5];
    const float* eb1        = (const float*)d_in[6];
    const float* attn_in_w  = (const float*)d_in[7];
    const float* attn_in_b  = (const float*)d_in[8];
    const float* attn_out_w = (const float*)d_in[9];
    const float* attn_out_b = (const float*)d_in[10];
    const float* dWih0      = (const float*)d_in[11];
    const float* dWhh0      = (const float*)d_in[12];
    const float* db0        = (const float*)d_in[13];
    const float* dWih1      = (const float*)d_in[14];
    const float* dWhh1      = (const float*)d_in[15];
    const float* db1        = (const float*)d_in[16];
    const float* lin_w      = (const float*)d_in[17];
    const float* lin_b      = (const float*)d_in[18];
    float* Y  = (float*)d_out;

    // ws: X (32768*512 f32) | Hb (32768*128 f32) | Kb | Vt | Wb2 | b0p
    float* ws = (float*)d_ws;
    float* X  = ws;                                  // 64 MiB (also KVf scratch)
    float* Hb = X + (size_t)32768 * 512;             // 16 MiB
    unsigned short* Kb  = (unsigned short*)(Hb + (size_t)32768 * 128);  // 8 MiB
    unsigned short* Vt  = Kb + (size_t)BATCH * T_LEN * HID;             // 8 MiB
    unsigned short* Wb2 = Vt + (size_t)BATCH * HID * T_LEN;             // 688 KiB
    float* b0p = (float*)(Wb2 + W2_TOTAL);                              // 2 KiB

    const int M = T_LEN * BATCH;  // 32768

    static bool attr_set = false;
    if (!attr_set) {
        hipFuncSetAttribute((const void*)decoder3,
                            hipFuncAttributeMaxDynamicSharedMemorySize, 131072);
        attr_set = true;
    }

    // decoder weight prep (tiny)
    pack2<<<(W2_TOTAL + 255) / 256, 256, 0, stream>>>(attn_in_w, dWih0, dWhh0, dWih1, dWhh1, Wb2);
    fuse_wxc<<<256, 256, 0, stream>>>(dWih0, attn_out_w, Wb2);
    fuse_b0<<<4, 128, 0, stream>>>(dWih0, attn_out_b, db0, b0p);

    // encoder layer 0
    gemm_bias<<<dim3(4, M/128), 256, 0, stream>>>(cnn, eWih0, eb0, X, M, 512, 1024);
    lstm_rec<<<BATCH, 512, 0, stream>>>(X, eWhh0, Hb);
    // encoder layer 1
    gemm_bias<<<dim3(4, M/128), 256, 0, stream>>>(Hb, eWih1, eb1, X, M, 512, 128);
    lstm_rec<<<BATCH, 512, 0, stream>>>(X, eWhh1, Hb);   // Hb = enc
    // KV = enc @ [Wk;Wv]^T + [bk;bv]  -> fp32 scratch in X
    gemm_bias<<<dim3(2, M/128), 256, 0, stream>>>(Hb, attn_in_w + 128*128, attn_in_b + 128,
                                                  X, M, 256, 128);
    kv_pack<<<256, 256, 0, stream>>>(X, Kb, Vt);
    // decoder (128 KiB dynamic LDS for K)
    decoder3<<<BATCH, 512, 131072, stream>>>(Kb, Vt, Wb2, b0p,
                                             attn_in_b, db1, lin_w, lin_b, Y);
}

// Round 4
// 6044.431 us; speedup vs baseline: 2.3886x; 2.0438x over previous
//
#include <hip/hip_runtime.h>
#include <math.h>

#define T_LEN 512
#define BATCH 64
#define HID 128
#define G4 512   // 4*HID
#define NWG 64

// bf16-packed decoder weight block (elements)
#define OFF_WQ2   0        // Wq            128x128
#define OFF_WXO   16384    // Wih0[:,0:128] 512x128
#define OFF_WXC   81920    // Wih0[:,128:]@Ow fused  512x128
#define OFF_WHH0b 147456   // Whh0          512x128
#define OFF_WIH1b 212992   // Wih1          512x128
#define OFF_WHH1b 278528   // Whh1          512x128
#define W2_TOTAL  344064

__device__ __forceinline__ float sigf(float x) { return 1.0f / (1.0f + __expf(-x)); }

__device__ __forceinline__ unsigned short f2bf(float x) {
    unsigned u = __float_as_uint(x);
    unsigned r = (u + 0x7fffu + ((u >> 16) & 1u)) >> 16;
    return (unsigned short)r;
}

__device__ __forceinline__ void cvt8(uint4 u, float f[8]) {
    f[0] = __uint_as_float(u.x << 16); f[1] = __uint_as_float(u.x & 0xffff0000u);
    f[2] = __uint_as_float(u.y << 16); f[3] = __uint_as_float(u.y & 0xffff0000u);
    f[4] = __uint_as_float(u.z << 16); f[5] = __uint_as_float(u.z & 0xffff0000u);
    f[6] = __uint_as_float(u.w << 16); f[7] = __uint_as_float(u.w & 0xffff0000u);
}

// ---------------------------------------------------------------------------
// C[M,N] = A[M,K] @ W[N,K]^T + bias[N]   (fp32, 128x128 tile, 8x8 microtile)
// ---------------------------------------------------------------------------
__global__ __launch_bounds__(256) void gemm_bias(
    const float* __restrict__ A, const float* __restrict__ W,
    const float* __restrict__ bias, float* __restrict__ C,
    int M, int N, int K)
{
    __shared__ __align__(16) float As[16][128];
    __shared__ __align__(16) float Ws[16][128];
    const int tid = threadIdx.x;
    const int m0 = blockIdx.y * 128;
    const int n0 = blockIdx.x * 128;
    const int tx = tid & 15, ty = tid >> 4;
    const int lrow = tid >> 1, lk = (tid & 1) * 8;
    float acc[8][8] = {};
    for (int k0 = 0; k0 < K; k0 += 16) {
        const float* Ap = A + (size_t)(m0 + lrow) * K + k0 + lk;
        const float* Wp = W + (size_t)(n0 + lrow) * K + k0 + lk;
        float4 a0 = *(const float4*)Ap;
        float4 a1 = *(const float4*)(Ap + 4);
        float4 w0 = *(const float4*)Wp;
        float4 w1 = *(const float4*)(Wp + 4);
        __syncthreads();
        As[lk+0][lrow]=a0.x; As[lk+1][lrow]=a0.y; As[lk+2][lrow]=a0.z; As[lk+3][lrow]=a0.w;
        As[lk+4][lrow]=a1.x; As[lk+5][lrow]=a1.y; As[lk+6][lrow]=a1.z; As[lk+7][lrow]=a1.w;
        Ws[lk+0][lrow]=w0.x; Ws[lk+1][lrow]=w0.y; Ws[lk+2][lrow]=w0.z; Ws[lk+3][lrow]=w0.w;
        Ws[lk+4][lrow]=w1.x; Ws[lk+5][lrow]=w1.y; Ws[lk+6][lrow]=w1.z; Ws[lk+7][lrow]=w1.w;
        __syncthreads();
        #pragma unroll
        for (int kk = 0; kk < 16; ++kk) {
            float4 av0 = *(const float4*)&As[kk][ty*8];
            float4 av1 = *(const float4*)&As[kk][ty*8+4];
            float4 wv0 = *(const float4*)&Ws[kk][tx*8];
            float4 wv1 = *(const float4*)&Ws[kk][tx*8+4];
            float av[8] = {av0.x,av0.y,av0.z,av0.w,av1.x,av1.y,av1.z,av1.w};
            float wv[8] = {wv0.x,wv0.y,wv0.z,wv0.w,wv1.x,wv1.y,wv1.z,wv1.w};
            #pragma unroll
            for (int i = 0; i < 8; ++i)
                #pragma unroll
                for (int j = 0; j < 8; ++j)
                    acc[i][j] = fmaf(av[i], wv[j], acc[i][j]);
        }
    }
    float bj[8];
    #pragma unroll
    for (int j = 0; j < 8; ++j) bj[j] = bias[n0 + tx*8 + j];
    #pragma unroll
    for (int i = 0; i < 8; ++i) {
        float* cp = C + (size_t)(m0 + ty*8 + i) * N + n0 + tx*8;
        *(float4*)cp     = make_float4(acc[i][0]+bj[0], acc[i][1]+bj[1], acc[i][2]+bj[2], acc[i][3]+bj[3]);
        *(float4*)(cp+4) = make_float4(acc[i][4]+bj[4], acc[i][5]+bj[5], acc[i][6]+bj[6], acc[i][7]+bj[7]);
    }
}

// ---------------------------------------------------------------------------
// LSTM recurrence, one workgroup per batch element, with X prefetch.
// ---------------------------------------------------------------------------
__global__ __launch_bounds__(512) void lstm_rec(
    const float* __restrict__ X,
    const float* __restrict__ Whh,
    float* __restrict__ Hout)
{
    const int b = blockIdx.x;
    const int r = threadIdx.x;
    __shared__ __align__(16) float h_s[HID];
    __shared__ float gate_s[G4];
    float w[HID];
    #pragma unroll
    for (int k = 0; k < HID; k += 4) {
        float4 v = *(const float4*)(Whh + (size_t)r * HID + k);
        w[k] = v.x; w[k+1] = v.y; w[k+2] = v.z; w[k+3] = v.w;
    }
    float c = 0.f;
    if (r < HID) h_s[r] = 0.f;
    __syncthreads();
    float xv = X[(size_t)b * G4 + r];
    for (int t = 0; t < T_LEN; ++t) {
        float xnext = 0.f;
        if (t + 1 < T_LEN) xnext = X[(size_t)((t + 1) * BATCH + b) * G4 + r];
        float a0 = xv, a1 = 0.f, a2 = 0.f, a3 = 0.f;
        const float4* h4 = (const float4*)h_s;
        #pragma unroll
        for (int k = 0; k < HID/4; ++k) {
            float4 hv = h4[k];
            a0 = fmaf(w[4*k+0], hv.x, a0);
            a1 = fmaf(w[4*k+1], hv.y, a1);
            a2 = fmaf(w[4*k+2], hv.z, a2);
            a3 = fmaf(w[4*k+3], hv.w, a3);
        }
        gate_s[r] = (a0 + a1) + (a2 + a3);
        __syncthreads();
        if (r < HID) {
            float gi = gate_s[r], gf = gate_s[HID+r], gg = gate_s[2*HID+r], go = gate_s[3*HID+r];
            c = sigf(gf) * c + sigf(gi) * tanhf(gg);
            float h = sigf(go) * tanhf(c);
            h_s[r] = h;
            Hout[(size_t)(t * BATCH + b) * HID + r] = h;
        }
        __syncthreads();
        xv = xnext;
    }
}

// ---------------------------------------------------------------------------
// KV repack: KVf (t*B+b, 256) fp32 -> Kb[b][t][128] bf16, Vt[b][d][512] bf16
// ---------------------------------------------------------------------------
__global__ __launch_bounds__(256) void kv_pack(
    const float* __restrict__ KVf, unsigned short* __restrict__ Kb,
    unsigned short* __restrict__ Vt)
{
    const int b = blockIdx.x & 63, tc = blockIdx.x >> 6;
    const int t0 = tc * 128;
    __shared__ unsigned short tile[128][130];
    const int half = threadIdx.x >> 7;      // 0/1
    const int d = threadIdx.x & 127;
    for (int tt = 0; tt < 128; tt += 2) {
        int trow = tt + half;
        int t = t0 + trow;
        const float* src = KVf + ((size_t)t * BATCH + b) * 256;
        Kb[((size_t)b * T_LEN + t) * HID + d] = f2bf(src[d]);
        tile[trow][d] = f2bf(src[128 + d]);
    }
    __syncthreads();
    for (int dd = 0; dd < 128; dd += 2) {
        int drow = dd + half;
        int ts = threadIdx.x & 127;
        Vt[((size_t)b * HID + drow) * T_LEN + t0 + ts] = tile[ts][drow];
    }
}

// ---------------------------------------------------------------------------
// pack2: fp32 -> bf16 for all decoder weights except the fused W_xc block
// ---------------------------------------------------------------------------
__global__ __launch_bounds__(256) void pack2(
    const float* __restrict__ attn_in_w,
    const float* __restrict__ dWih0, const float* __restrict__ dWhh0,
    const float* __restrict__ dWih1, const float* __restrict__ dWhh1,
    unsigned short* __restrict__ Wb2)
{
    int i = blockIdx.x * 256 + threadIdx.x;
    if (i >= W2_TOTAL) return;
    if (i >= OFF_WXC && i < OFF_WHH0b) return;   // filled by fuse_wxc
    float v;
    if (i < OFF_WXO) v = attn_in_w[i];                       // Wq rows 0..127
    else if (i < OFF_WXC) {
        int j = i - OFF_WXO; v = dWih0[(size_t)(j >> 7) * 256 + (j & 127)];
    }
    else if (i < OFF_WIH1b) v = dWhh0[i - OFF_WHH0b];
    else if (i < OFF_WHH1b) v = dWih1[i - OFF_WIH1b];
    else                    v = dWhh1[i - OFF_WHH1b];
    Wb2[i] = f2bf(v);
}

// ---------------------------------------------------------------------------
// W_xc[r][c] = sum_j Wih0[r][128+j] * Ow[j][c]   (bf16 out)
// ---------------------------------------------------------------------------
__global__ __launch_bounds__(256) void fuse_wxc(
    const float* __restrict__ dWih0, const float* __restrict__ ow,
    unsigned short* __restrict__ Wb2)
{
    __shared__ float ow_s[128 * 128];
    for (int i = threadIdx.x; i < 16384; i += 256) ow_s[i] = ow[i];
    __syncthreads();
    const int r = blockIdx.x * 2 + (threadIdx.x >> 7);
    const int c = threadIdx.x & 127;
    const float* wr = dWih0 + (size_t)r * 256 + 128;
    float acc = 0.f;
    #pragma unroll 8
    for (int j = 0; j < 128; ++j) acc = fmaf(wr[j], ow_s[j * 128 + c], acc);
    Wb2[OFF_WXC + r * 128 + c] = f2bf(acc);
}

// b0'[r] = b0[r] + sum_j Wih0[r][128+j] * ob[j]
__global__ __launch_bounds__(128) void fuse_b0(
    const float* __restrict__ dWih0, const float* __restrict__ ob,
    const float* __restrict__ db0, float* __restrict__ b0p)
{
    int r = blockIdx.x * 128 + threadIdx.x;
    const float* wr = dWih0 + (size_t)r * 256 + 128;
    float acc = db0[r];
    #pragma unroll 8
    for (int j = 0; j < 128; ++j) acc = fmaf(wr[j], ob[j], acc);
    b0p[r] = acc;
}

// ---------------------------------------------------------------------------
// Grid barrier (all 64 WGs co-resident; 1 WG/CU at this LDS usage)
// ---------------------------------------------------------------------------
__device__ __forceinline__ void gridbar(int* cnt, int* gen) {
    __syncthreads();
    if (threadIdx.x == 0) {
        __threadfence();   // write back my XCD's dirty lines
        int g = __hip_atomic_load(gen, __ATOMIC_RELAXED, __HIP_MEMORY_SCOPE_AGENT);
        if (__hip_atomic_fetch_add(cnt, 1, __ATOMIC_ACQ_REL, __HIP_MEMORY_SCOPE_AGENT) == NWG - 1) {
            __hip_atomic_store(cnt, 0, __ATOMIC_RELAXED, __HIP_MEMORY_SCOPE_AGENT);
            __hip_atomic_store(gen, g + 1, __ATOMIC_RELEASE, __HIP_MEMORY_SCOPE_AGENT);
        } else {
            while (__hip_atomic_load(gen, __ATOMIC_RELAXED, __HIP_MEMORY_SCOPE_AGENT) == g)
                __builtin_amdgcn_s_sleep(2);
        }
        __threadfence();   // invalidate L1/L2 for fresh cross-XCD reads
    }
    __syncthreads();
}

// ---------------------------------------------------------------------------
// Decoder v4: persistent cooperative, 64 WGs x 512 thr, 3 grid bars/step.
// WG w: attention for batch w (K in LDS); gate rows {2w,2w+1}x4 for ALL b
// (weight slice in LDS). Activations out/ctx/h0/h1 in global fp32.
// ---------------------------------------------------------------------------
__global__ __launch_bounds__(512) void decoder4(
    const unsigned short* __restrict__ Kb, const unsigned short* __restrict__ Vt,
    const unsigned short* __restrict__ Wb2, const float* __restrict__ b0p,
    const float* __restrict__ attn_b, const float* __restrict__ b1,
    const float* __restrict__ lw, const float* __restrict__ lb,
    float* __restrict__ outg, float* __restrict__ ctxg,
    float* __restrict__ h0g, float* __restrict__ h1g,
    int* bar, float* __restrict__ Y)
{
    extern __shared__ __align__(16) char dyn[];
    char* Kl = dyn;                               // 512x128 bf16 swizzled = 128 KiB
    const int w = blockIdx.x;
    const int tid = threadIdx.x;
    __shared__ __align__(16) unsigned short Ws0[8][384];  // wxo|wxc|whh0 rows
    __shared__ __align__(16) unsigned short Ws1[8][256];  // wih1|whh1 rows
    __shared__ __align__(16) float sc[4 * T_LEN];
    __shared__ float red[512];
    __shared__ __align__(16) float out_s[HID];
    __shared__ __align__(16) float q_s[HID];
    __shared__ __align__(16) float ctxp[4][HID];
    __shared__ float g_s[8][64];
    __shared__ float hmax[4], hden[4];

    // ---- stage K (batch w) into LDS, swizzled ----
    {
        const unsigned short* Ksrc = Kb + (size_t)w * T_LEN * HID;
        for (int c = tid; c < T_LEN * HID / 8; c += 512) {
            int t = c >> 4, k16 = c & 15;
            uint4 v = *(const uint4*)(Ksrc + c * 8);
            *(uint4*)(Kl + t * 256 + ((k16 * 16) ^ ((t & 7) << 4))) = v;
        }
    }
    // ---- stage gate-weight slices into LDS ----
    {
        for (int idx = tid; idx < 384; idx += 512) {            // Ws0: 8 x 48 chunks
            int rl = idx / 48, c8 = (idx % 48) * 8;
            int r = (rl >> 1) * 128 + 2 * w + (rl & 1);
            const unsigned short* src;
            if (c8 < 128)      src = Wb2 + OFF_WXO   + (size_t)r * 128 + c8;
            else if (c8 < 256) src = Wb2 + OFF_WXC   + (size_t)r * 128 + (c8 - 128);
            else               src = Wb2 + OFF_WHH0b + (size_t)r * 128 + (c8 - 256);
            *(uint4*)&Ws0[rl][c8] = *(const uint4*)src;
        }
        for (int idx = tid; idx < 256; idx += 512) {            // Ws1: 8 x 32 chunks
            int rl = idx / 32, c8 = (idx % 32) * 8;
            int r = (rl >> 1) * 128 + 2 * w + (rl & 1);
            const unsigned short* src = (c8 < 128)
                ? Wb2 + OFF_WIH1b + (size_t)r * 128 + c8
                : Wb2 + OFF_WHH1b + (size_t)r * 128 + (c8 - 128);
            *(uint4*)&Ws1[rl][c8] = *(const uint4*)src;
        }
    }
    // ---- per-thread register pins ----
    const int r_local = tid >> 6;                 // 0..7 : gate-row slot
    const int bb = tid & 63;                      // batch for gate phases
    const int r_g = (r_local >> 1) * 128 + 2 * w + (r_local & 1);
    const float b0r = b0p[r_g];
    const float b1r = b1[r_g];
    const int qrow = tid >> 2, qpart = tid & 3;
    const unsigned short* wqp = Wb2 + OFF_WQ2 + (size_t)qrow * 128 + qpart * 32;
    uint4 wq0 = *(const uint4*)(wqp);
    uint4 wq1 = *(const uint4*)(wqp + 8);
    uint4 wq2 = *(const uint4*)(wqp + 16);
    uint4 wq3 = *(const uint4*)(wqp + 24);
    const float bqv = attn_b[qrow];
    float c0 = 0.f, c1 = 0.f;
    // zero-init activations (own slice)
    if (tid < 128) {
        int zb = tid & 63, hh = tid >> 6;
        int off = zb * HID + 2 * w + hh;
        outg[off] = 0.f; h0g[off] = 0.f; h1g[off] = 0.f;   // parity 0
    }
    const float scale = 0.17677669529663687f;   // 1/sqrt(32)
    const int g = tid >> 7, l = tid & 127;

    for (int step = 0; step < 64; ++step) {
        const int pr = step & 1, pw = pr ^ 1;
        gridbar(bar, bar + 1);                    // out/h1 of prev step visible
        // ================= Phase B': attention for batch w =================
        if (tid < HID) out_s[tid] = outg[w * HID + tid];
        __syncthreads();
        // q = (Wq @ out + bq) * scale ; 4 threads/row, weights in registers
        {
            float acc = 0.f; float f[8];
            const float* os = out_s + qpart * 32;
            cvt8(wq0, f);
            acc += f[0]*os[0]+f[1]*os[1]+f[2]*os[2]+f[3]*os[3]+f[4]*os[4]+f[5]*os[5]+f[6]*os[6]+f[7]*os[7];
            cvt8(wq1, f);
            acc += f[0]*os[8]+f[1]*os[9]+f[2]*os[10]+f[3]*os[11]+f[4]*os[12]+f[5]*os[13]+f[6]*os[14]+f[7]*os[15];
            cvt8(wq2, f);
            acc += f[0]*os[16]+f[1]*os[17]+f[2]*os[18]+f[3]*os[19]+f[4]*os[20]+f[5]*os[21]+f[6]*os[22]+f[7]*os[23];
            cvt8(wq3, f);
            acc += f[0]*os[24]+f[1]*os[25]+f[2]*os[26]+f[3]*os[27]+f[4]*os[28]+f[5]*os[29]+f[6]*os[30]+f[7]*os[31];
            acc += __shfl_xor(acc, 1);
            acc += __shfl_xor(acc, 2);
            if (qpart == 0) q_s[qrow] = (acc + bqv) * scale;
        }
        __syncthreads();
        // scores from LDS K (swizzled), thread t = tid, 4 heads
        {
            const int t = tid;
            float acc[4] = {0.f, 0.f, 0.f, 0.f};
            #pragma unroll
            for (int k16 = 0; k16 < 16; ++k16) {
                uint4 u = *(const uint4*)(Kl + t * 256 + ((k16 * 16) ^ ((t & 7) << 4)));
                float f[8]; cvt8(u, f);
                float4 q0 = *(const float4*)(q_s + k16 * 8);
                float4 q1 = *(const float4*)(q_s + k16 * 8 + 4);
                acc[k16 >> 2] += f[0]*q0.x + f[1]*q0.y + f[2]*q0.z + f[3]*q0.w
                               + f[4]*q1.x + f[5]*q1.y + f[6]*q1.z + f[7]*q1.w;
            }
            #pragma unroll
            for (int h = 0; h < 4; ++h) sc[h * T_LEN + t] = acc[h];
        }
        __syncthreads();
        // softmax per head
        float v[4];
        float mx = -3.4e38f;
        #pragma unroll
        for (int i = 0; i < 4; ++i) { v[i] = sc[g*T_LEN + l + 128*i]; mx = fmaxf(mx, v[i]); }
        red[tid] = mx;
        __syncthreads();
        if (l < 64) {
            float m2 = fmaxf(red[g*128 + l], red[g*128 + l + 64]);
            #pragma unroll
            for (int s = 32; s > 0; s >>= 1) m2 = fmaxf(m2, __shfl_xor(m2, s, 64));
            if (l == 0) hmax[g] = m2;
        }
        __syncthreads();
        float hm = hmax[g];
        float s4 = 0.f;
        #pragma unroll
        for (int i = 0; i < 4; ++i) {
            float e = __expf(v[i] - hm);
            sc[g*T_LEN + l + 128*i] = e;
            s4 += e;
        }
        red[tid] = s4;
        __syncthreads();
        if (l < 64) {
            float s2 = red[g*128 + l] + red[g*128 + l + 64];
            #pragma unroll
            for (int s = 32; s > 0; s >>= 1) s2 += __shfl_xor(s2, s, 64);
            if (l == 0) hden[g] = s2;
        }
        __syncthreads();
        // ctx from V (L2), write ctxg
        {
            const int d = tid & 127, ch = tid >> 7;
            const unsigned short* vr = Vt + ((size_t)w * HID + d) * T_LEN + ch * 128;
            const float* scr = sc + (d >> 5) * T_LEN + ch * 128;
            float acc = 0.f;
            #pragma unroll
            for (int k = 0; k < 128; k += 8) {
                float f[8]; cvt8(*(const uint4*)(vr + k), f);
                #pragma unroll
                for (int j = 0; j < 8; ++j) acc = fmaf(f[j], scr[k + j], acc);
            }
            ctxp[ch][d] = acc;
        }
        __syncthreads();
        if (tid < HID)
            ctxg[w * HID + tid] = (ctxp[0][tid] + ctxp[1][tid] + ctxp[2][tid] + ctxp[3][tid]) / hden[tid >> 5];
        // y of previous step (out_s = out^(step-1))
        if (tid < 3 && step > 0) {
            const float* wr = lw + tid * HID;
            float acc = lb[tid];
            #pragma unroll
            for (int k = 0; k < HID; k += 4) {
                float4 wv = *(const float4*)(wr + k);
                float4 ov = *(const float4*)(out_s + k);
                acc += wv.x*ov.x + wv.y*ov.y + wv.z*ov.z + wv.w*ov.w;
            }
            Y[((size_t)(step - 1) * BATCH + w) * 3 + tid] = acc;
        }
        gridbar(bar, bar + 1);
        // ================= Phase C: gates0, all batches, own rows ==========
        {
            const float* ob = outg + bb * HID;
            const float* cb = ctxg + bb * HID;
            const float* hb = h0g + pr * (BATCH * HID) + bb * HID;
            const unsigned short* wrow = &Ws0[r_local][0];
            float acc = b0r;
            #pragma unroll
            for (int k = 0; k < HID; k += 8) {
                float f[8]; cvt8(*(const uint4*)(wrow + k), f);
                float4 a0 = *(const float4*)(ob + k), a1 = *(const float4*)(ob + k + 4);
                acc += f[0]*a0.x + f[1]*a0.y + f[2]*a0.z + f[3]*a0.w
                     + f[4]*a1.x + f[5]*a1.y + f[6]*a1.z + f[7]*a1.w;
            }
            #pragma unroll
            for (int k = 0; k < HID; k += 8) {
                float f[8]; cvt8(*(const uint4*)(wrow + 128 + k), f);
                float4 a0 = *(const float4*)(cb + k), a1 = *(const float4*)(cb + k + 4);
                acc += f[0]*a0.x + f[1]*a0.y + f[2]*a0.z + f[3]*a0.w
                     + f[4]*a1.x + f[5]*a1.y + f[6]*a1.z + f[7]*a1.w;
            }
            #pragma unroll
            for (int k = 0; k < HID; k += 8) {
                float f[8]; cvt8(*(const uint4*)(wrow + 256 + k), f);
                float4 a0 = *(const float4*)(hb + k), a1 = *(const float4*)(hb + k + 4);
                acc += f[0]*a0.x + f[1]*a0.y + f[2]*a0.z + f[3]*a0.w
                     + f[4]*a1.x + f[5]*a1.y + f[6]*a1.z + f[7]*a1.w;
            }
            g_s[r_local][bb] = acc;
        }
        __syncthreads();
        if (tid < 128) {
            const int hh = tid >> 6, zb = tid & 63;
            float gi = g_s[0 + hh][zb], gf = g_s[2 + hh][zb];
            float gg = g_s[4 + hh][zb], go = g_s[6 + hh][zb];
            c0 = sigf(gf) * c0 + sigf(gi) * tanhf(gg);
            float h = sigf(go) * tanhf(c0);
            h0g[pw * (BATCH * HID) + zb * HID + 2 * w + hh] = h;
        }
        gridbar(bar, bar + 1);
        // ================= Phase D: gates1, all batches, own rows ==========
        {
            const float* hb0 = h0g + pw * (BATCH * HID) + bb * HID;   // fresh h0
            const float* hb1 = h1g + pr * (BATCH * HID) + bb * HID;   // prev h1
            const unsigned short* wrow = &Ws1[r_local][0];
            float acc = b1r;
            #pragma unroll
            for (int k = 0; k < HID; k += 8) {
                float f[8]; cvt8(*(const uint4*)(wrow + k), f);
                float4 a0 = *(const float4*)(hb0 + k), a1 = *(const float4*)(hb0 + k + 4);
                acc += f[0]*a0.x + f[1]*a0.y + f[2]*a0.z + f[3]*a0.w
                     + f[4]*a1.x + f[5]*a1.y + f[6]*a1.z + f[7]*a1.w;
            }
            #pragma unroll
            for (int k = 0; k < HID; k += 8) {
                float f[8]; cvt8(*(const uint4*)(wrow + 128 + k), f);
                float4 a0 = *(const float4*)(hb1 + k), a1 = *(const float4*)(hb1 + k + 4);
                acc += f[0]*a0.x + f[1]*a0.y + f[2]*a0.z + f[3]*a0.w
                     + f[4]*a1.x + f[5]*a1.y + f[6]*a1.z + f[7]*a1.w;
            }
            g_s[r_local][bb] = acc;
        }
        __syncthreads();
        if (tid < 128) {
            const int hh = tid >> 6, zb = tid & 63;
            float gi = g_s[0 + hh][zb], gf = g_s[2 + hh][zb];
            float gg = g_s[4 + hh][zb], go = g_s[6 + hh][zb];
            c1 = sigf(gf) * c1 + sigf(gi) * tanhf(gg);
            float h = sigf(go) * tanhf(c1);
            h1g[pw * (BATCH * HID) + zb * HID + 2 * w + hh] = h;
            outg[zb * HID + 2 * w + hh] = fmaxf(h, 0.f);
        }
    }
    gridbar(bar, bar + 1);
    // final y (step 63)
    if (tid < 3) {
        const float* wr = lw + tid * HID;
        const float* ob = outg + w * HID;
        float acc = lb[tid];
        #pragma unroll
        for (int k = 0; k < HID; k += 4) {
            float4 wv = *(const float4*)(wr + k);
            float4 ov = *(const float4*)(ob + k);
            acc += wv.x*ov.x + wv.y*ov.y + wv.z*ov.z + wv.w*ov.w;
        }
        Y[((size_t)63 * BATCH + w) * 3 + tid] = acc;
    }
}

// ---------------------------------------------------------------------------
extern "C" void kernel_launch(void* const* d_in, const int* in_sizes, int n_in,
                              void* d_out, int out_size, void* d_ws, size_t ws_size,
                              hipStream_t stream) {
    const float* cnn        = (const float*)d_in[0];
    const float* eWih0      = (const float*)d_in[1];
    const float* eWhh0      = (const float*)d_in[2];
    const float* eb0        = (const float*)d_in[3];
    const float* eWih1      = (const float*)d_in[4];
    const float* eWhh1      = (const float*)d_in[5];
    const float* eb1        = (const float*)d_in[6];
    const float* attn_in_w  = (const float*)d_in[7];
    const float* attn_in_b  = (const float*)d_in[8];
    const float* attn_out_w = (const float*)d_in[9];
    const float* attn_out_b = (const float*)d_in[10];
    const float* dWih0      = (const float*)d_in[11];
    const float* dWhh0      = (const float*)d_in[12];
    const float* db0        = (const float*)d_in[13];
    const float* dWih1      = (const float*)d_in[14];
    const float* dWhh1      = (const float*)d_in[15];
    const float* db1        = (const float*)d_in[16];
    const float* lin_w      = (const float*)d_in[17];
    const float* lin_b      = (const float*)d_in[18];
    float* Y  = (float*)d_out;

    // ws: X (32768*512 f32) | Hb (32768*128 f32) | Kb | Vt | Wb2 | b0p | bar | acts
    float* ws = (float*)d_ws;
    float* X  = ws;                                  // 64 MiB (also KVf scratch)
    float* Hb = X + (size_t)32768 * 512;             // 16 MiB
    unsigned short* Kb  = (unsigned short*)(Hb + (size_t)32768 * 128);  // 8 MiB
    unsigned short* Vt  = Kb + (size_t)BATCH * T_LEN * HID;             // 8 MiB
    unsigned short* Wb2 = Vt + (size_t)BATCH * HID * T_LEN;             // 688 KiB
    float* b0p  = (float*)(Wb2 + W2_TOTAL);                             // 2 KiB
    int*   bar  = (int*)(b0p + 512);                                    // 8 B
    float* outg = (float*)(bar + 4);                                    // 32 KiB
    float* ctxg = outg + BATCH * HID;
    float* h0g  = ctxg + BATCH * HID;                                   // 2x32 KiB
    float* h1g  = h0g + 2 * BATCH * HID;                                // 2x32 KiB

    const int M = T_LEN * BATCH;  // 32768

    hipFuncSetAttribute((const void*)decoder4,
                        hipFuncAttributeMaxDynamicSharedMemorySize, 131072);

    hipMemsetAsync(bar, 0, 16, stream);

    // decoder weight prep (tiny)
    pack2<<<(W2_TOTAL + 255) / 256, 256, 0, stream>>>(attn_in_w, dWih0, dWhh0, dWih1, dWhh1, Wb2);
    fuse_wxc<<<256, 256, 0, stream>>>(dWih0, attn_out_w, Wb2);
    fuse_b0<<<4, 128, 0, stream>>>(dWih0, attn_out_b, db0, b0p);

    // encoder layer 0
    gemm_bias<<<dim3(4, M/128), 256, 0, stream>>>(cnn, eWih0, eb0, X, M, 512, 1024);
    lstm_rec<<<BATCH, 512, 0, stream>>>(X, eWhh0, Hb);
    // encoder layer 1
    gemm_bias<<<dim3(4, M/128), 256, 0, stream>>>(Hb, eWih1, eb1, X, M, 512, 128);
    lstm_rec<<<BATCH, 512, 0, stream>>>(X, eWhh1, Hb);   // Hb = enc
    // KV = enc @ [Wk;Wv]^T + [bk;bv]  -> fp32 scratch in X
    gemm_bias<<<dim3(2, M/128), 256, 0, stream>>>(Hb, attn_in_w + 128*128, attn_in_b + 128,
                                                  X, M, 256, 128);
    kv_pack<<<256, 256, 0, stream>>>(X, Kb, Vt);
    // decoder: persistent cooperative, 64 WGs
    decoder4<<<NWG, 512, 131072, stream>>>(Kb, Vt, Wb2, b0p,
                                           attn_in_b, db1, lin_w, lin_b,
                                           outg, ctxg, h0g, h1g, bar, Y);
}